// Round 15
// baseline (354.146 us; speedup 1.0000x reference)
//
#include <hip/hip_runtime.h>
#include <hip/hip_bf16.h>

#define DI __device__ __forceinline__

typedef __attribute__((ext_vector_type(4))) float  f32x4;
typedef __attribute__((ext_vector_type(8))) short  s16x8;
typedef __attribute__((ext_vector_type(4))) short  s16x4;
typedef __attribute__((ext_vector_type(8))) __bf16 bf16x8;

// ---------- helpers ----------
DI short f2bf(float f) {
  union { float f; unsigned u; } v; v.f = f;
  unsigned r = v.u + 0x7fffu + ((v.u >> 16) & 1u);   // RNE
  return (short)(r >> 16);
}
DI float bf2f(short s) {
  union { unsigned u; float f; } v; v.u = ((unsigned)(unsigned short)s) << 16;
  return v.f;
}

DI f32x4 mfma16(s16x8 a, s16x8 b, f32x4 c) {
  return __builtin_amdgcn_mfma_f32_16x16x32_bf16(
      __builtin_bit_cast(bf16x8, a), __builtin_bit_cast(bf16x8, b), c, 0, 0, 0);
}

typedef const __attribute__((address_space(1))) unsigned* gas_p;
typedef __attribute__((address_space(3))) unsigned* las_p;
DI void gload16(const void* g, void* l) {
  __builtin_amdgcn_global_load_lds((gas_p)g, (las_p)l, 16, 0, 0);
}

template<int N> DI void wait_vmcnt() {
  asm volatile("s_waitcnt vmcnt(%0)" :: "n"(N) : "memory");
}

// ---------- f32 -> bf16 cast ----------
__global__ __launch_bounds__(256) void cast_bf16(const float* __restrict__ x,
                                                 short* __restrict__ y) {
  const int i = (blockIdx.x * 256 + threadIdx.x) * 4;
  const float4 t = *(const float4*)&x[i];
  s16x4 o;
  o[0] = f2bf(t.x); o[1] = f2bf(t.y); o[2] = f2bf(t.z); o[3] = f2bf(t.w);
  *(s16x4*)&y[i] = o;
}

// ---------- weight transpose+cast: W[K,N] f32 -> Wt[N,K] bf16 ----------
struct TJob { const float* src; short* dst; int K, N, tile0; };
struct TJobs { TJob j[12]; };

__global__ __launch_bounds__(256) void transpose_w(TJobs jobs) {
  __shared__ float T[32][33];
  const int t = blockIdx.x;
  int ji = 0;
#pragma unroll
  for (int i = 1; i < 12; ++i) if (jobs.j[i].tile0 <= t) ji = i;
  const float* src = jobs.j[ji].src;
  short* dst = jobs.j[ji].dst;
  const int K = jobs.j[ji].K, N = jobs.j[ji].N;
  const int lt = t - jobs.j[ji].tile0;
  const int tn = N >> 5;
  const int n0 = (lt % tn) << 5, k0 = (lt / tn) << 5;
  const int tid = threadIdx.x;
#pragma unroll
  for (int i = 0; i < 4; ++i) {
    const int c = i * 256 + tid, r = c >> 5, cc = c & 31;
    T[cc][r] = src[(long long)(k0 + r) * N + n0 + cc];
  }
  __syncthreads();
#pragma unroll
  for (int i = 0; i < 4; ++i) {
    const int c = i * 256 + tid, r = c >> 5, cc = c & 31;
    dst[(long long)(n0 + r) * K + k0 + cc] = f2bf(T[r][cc]);
  }
}

// ---------- 4-wave MFMA GEMM: C = A[M,K] @ B[N,K]^T ----------
// 3-ring LDS, counted vmcnt, raw s_barrier, XOR-swizzled LDS (0 conflicts),
// swapped-operand MFMA (lane holds 4 consecutive C-cols), T1 XCD-chunked
// blockIdx swizzle (bijective when nx*ny % 8 == 0; identity otherwise).
// z = zb*nSplit+zs; zs selects K-slice.  bias2: per-zb bias (batched paths).
// EPI 0: bf16 +bias. EPI 1: bf16 gelu(x+bias). EPI 2: bf16 raw partial.
// EPI 3: bf16 +bias for cols<1536; cols>=1536 write ONLY V^T to
//        vtOut[zb][bh][d][s] (qkv V-columns are dead downstream).
template<int BM, int BN, int WM, int WN, int EPI>
__global__ __launch_bounds__(256) void gemm_bt(
    const short* __restrict__ A, int lda, long long sA,
    const short* __restrict__ B, int ldb, long long sB,
    void* __restrict__ Cv, int ldc,
    long long cOuter, int cInner, int cStride,
    const float* __restrict__ bias, const float* __restrict__ bias2,
    int K, int nSplit,
    short* __restrict__ vtOut) {
  constexpr int BK = 32;
  constexpr int WNW = BN / WN;
  constexpr int MFR = WM / 16, NFR = WN / 16;
  constexpr int ALD = BM / 64;
  constexpr int BLD = BN / 64;
  constexpr int LPT = ALD + BLD;

  __shared__ short As[3][BM * BK];
  __shared__ short Bs[3][BN * BK];

  const int z = blockIdx.z;
  const int zb = z / nSplit, zs = z - zb * nSplit;
  const short* Ab = A + (long long)zb * sA + (long long)zs * K;
  const short* Bb = B + (long long)zb * sB + (long long)zs * K;
  const long long cOff = (long long)(z / cInner) * cOuter + (long long)(z % cInner) * cStride;
  const float* bi = (bias2 && zb) ? bias2 : bias;

  // T1: XCD-chunked swizzle of the xy-plane (x-fastest linearization)
  int bxi = blockIdx.x, byi = blockIdx.y;
  {
    const int nx = gridDim.x;
    const int nwg = nx * gridDim.y;
    if ((nwg & 7) == 0) {
      int id = byi * nx + bxi;
      id = (id & 7) * (nwg >> 3) + (id >> 3);
      bxi = id % nx;
      byi = id / nx;
    }
  }
  const int bm = bxi * BM;
  const int bn = byi * BN;
  const int tid = threadIdx.x;
  const int wave = tid >> 6, lane = tid & 63;
  const int wm = (wave / WNW) * WM;
  const int wn = (wave % WNW) * WN;
  const int l16 = lane & 15, lk = lane >> 4;

  const int scol = ((tid & 3) ^ ((tid >> 3) & 3)) * 8;
  const short* aBase = Ab + (long long)(bm + (tid >> 2)) * lda + scol;
  const short* bBase = Bb + (long long)(bn + (tid >> 2)) * ldb + scol;
  const int ldsOff = wave * 64 * 8;
  const int rslot = (lk ^ ((l16 >> 1) & 3)) * 8;

  f32x4 acc[MFR][NFR] = {};

  auto stage = [&](int buf, int kt) {
#pragma unroll
    for (int i = 0; i < ALD; ++i)
      gload16(aBase + kt + (long long)(i * 64) * lda, &As[buf][i * 2048 + ldsOff]);
#pragma unroll
    for (int i = 0; i < BLD; ++i)
      gload16(bBase + kt + (long long)(i * 64) * ldb, &Bs[buf][i * 2048 + ldsOff]);
  };

  const int nt = K / BK;
  stage(0, 0);
  if (nt > 1) stage(1, BK);
  int cur = 0;
  for (int t = 0; t < nt; ++t) {
    if (t + 1 < nt) wait_vmcnt<LPT>();
    else            wait_vmcnt<0>();
    __builtin_amdgcn_s_barrier();
    s16x8 af[MFR], bfr[NFR];
#pragma unroll
    for (int mi = 0; mi < MFR; ++mi)
      af[mi] = *(const s16x8*)&As[cur][(wm + mi * 16 + l16) * BK + rslot];
#pragma unroll
    for (int ni = 0; ni < NFR; ++ni)
      bfr[ni] = *(const s16x8*)&Bs[cur][(wn + ni * 16 + l16) * BK + rslot];
#pragma unroll
    for (int mi = 0; mi < MFR; ++mi)
#pragma unroll
      for (int ni = 0; ni < NFR; ++ni)
        acc[mi][ni] = mfma16(bfr[ni], af[mi], acc[mi][ni]);
    if (t + 2 < nt) {
      const int nb = cur + 2 >= 3 ? cur - 1 : cur + 2;
      stage(nb, (t + 2) * BK);
    }
    cur = (cur + 1 == 3) ? 0 : cur + 1;
  }

#pragma unroll
  for (int mi = 0; mi < MFR; ++mi) {
    const int row = bm + wm + mi * 16 + l16;
#pragma unroll
    for (int ni = 0; ni < NFR; ++ni) {
      const int col = bn + wn + ni * 16 + lk * 4;
      const long long idx = cOff + (long long)row * ldc + col;
      f32x4 bv = {};
      if (EPI != 2 && bi) bv = *(const f32x4*)&bi[col];
      f32x4 v = acc[mi][ni] + bv;
      if constexpr (EPI == 0 || EPI == 2 || EPI == 3) {
        s16x4 o;
#pragma unroll
        for (int r = 0; r < 4; ++r) o[r] = f2bf(v[r]);
        if constexpr (EPI == 3) {
          if (col >= 1536) {   // block-uniform (128-tile never straddles 1536)
            const int b = row >> 9, s = row & 511;
            const int hc = col - 1536;
            const int bh = b * 12 + (hc >> 6);
            const int d0 = hc & 63;
            short* vp = vtOut + (long long)zb * 3145728 +
                        (long long)bh * 32768 + (long long)d0 * 512 + s;
#pragma unroll
            for (int r = 0; r < 4; ++r) vp[r * 512] = o[r];
          } else {
            *(s16x4*)&((short*)Cv)[idx] = o;
          }
        } else {
          *(s16x4*)&((short*)Cv)[idx] = o;
        }
      } else {  // EPI 1
        s16x4 o;
#pragma unroll
        for (int r = 0; r < 4; ++r) {
          const float g = 0.5f * v[r] * (1.f + erff(v[r] * 0.70710678118654752f));
          o[r] = f2bf(g);
        }
        *(s16x4*)&((short*)Cv)[idx] = o;
      }
    }
  }
}

// ---------- fused scores + softmax + PV -> ctx (bf16), one path per dispatch ----------
// QK^T via MFMA (Q,K staged in LDS), softmax in registers, P -> LDS (aliased
// on dead Ks buffer, chunk-XOR swizzled), PV streams V^T from global (L2-hot).
template<int HIER>
__global__ __launch_bounds__(256) void attn_fused(
    const short* __restrict__ QKV,
    const float* __restrict__ amask,
    const int* __restrict__ hmask,
    const short* __restrict__ Vt,
    short* __restrict__ ctx) {
  __shared__ short Qs[32 * 64];
  __shared__ short Ks[256 * 64];        // reused as Ps[32][512] after scores
  __shared__ float red[32 * 4];
  __shared__ int   hm[512];

  const int bh = blockIdx.y;
  const int b = bh / 12, hh = bh % 12;
  const int q0 = blockIdx.x * 32;
  const int tid = threadIdx.x;
  const int wave = tid >> 6, lane = tid & 63;
  const int l16 = lane & 15, lk = lane >> 4;
  const long long rowbase = (long long)(b * 512) * 2304 + hh * 64;

  {
    const int c = tid;
    const int d8 = ((c & 7) ^ ((c >> 3) & 7)) * 8;
    gload16(QKV + rowbase + (long long)(q0 + (c >> 3)) * 2304 + d8,
            &Qs[wave * 64 * 8]);
  }
  if constexpr (HIER) {
    for (int i = tid; i < 512; i += 256) hm[i] = hmask[b * 512 + i];
  }

  f32x4 acc[2][8] = {};
#pragma unroll
  for (int kc = 0; kc < 2; ++kc) {
    if (kc) __syncthreads();
#pragma unroll
    for (int i = 0; i < 8; ++i) {
      const int c = i * 256 + tid;
      const int d8 = ((c & 7) ^ ((c >> 3) & 7)) * 8;
      gload16(QKV + rowbase + 768 + (long long)(kc * 256 + (c >> 3)) * 2304 + d8,
              &Ks[(i * 256 + wave * 64) * 8]);
    }
    __syncthreads();
#pragma unroll
    for (int ks = 0; ks < 2; ++ks) {
      s16x8 af[2], bfr[4];
#pragma unroll
      for (int mi = 0; mi < 2; ++mi)
        af[mi] = *(const s16x8*)&Qs[(mi * 16 + l16) * 64 +
                                    (((ks * 4 + lk) ^ (l16 & 7)) * 8)];
#pragma unroll
      for (int ni = 0; ni < 4; ++ni)
        bfr[ni] = *(const s16x8*)&Ks[(wave * 64 + ni * 16 + l16) * 64 +
                                     (((ks * 4 + lk) ^ (l16 & 7)) * 8)];
#pragma unroll
      for (int mi = 0; mi < 2; ++mi)
#pragma unroll
        for (int ni = 0; ni < 4; ++ni)
          acc[mi][kc * 4 + ni] = mfma16(af[mi], bfr[ni], acc[mi][kc * 4 + ni]);
    }
  }

  int gq[2][4];
  if constexpr (HIER) {
#pragma unroll
    for (int mi = 0; mi < 2; ++mi)
#pragma unroll
      for (int r = 0; r < 4; ++r)
        gq[mi][r] = hm[q0 + mi * 16 + lk * 4 + r];
  }
  int hk[8]; float am[8];
#pragma unroll
  for (int nig = 0; nig < 8; ++nig) {
    const int col = (nig >> 2) * 256 + wave * 64 + (nig & 3) * 16 + l16;
    if constexpr (HIER) hk[nig] = hm[col];
    else                am[nig] = amask[b * 512 + col];
  }
#pragma unroll
  for (int mi = 0; mi < 2; ++mi)
#pragma unroll
    for (int nig = 0; nig < 8; ++nig)
#pragma unroll
      for (int r = 0; r < 4; ++r) {
        float v = acc[mi][nig][r] * 0.125f;
        if constexpr (HIER) v += (hk[nig] == gq[mi][r]) ? 0.f : -10000.f;
        else                v += am[nig];
        acc[mi][nig][r] = v;
      }

  float mx[2][4];
#pragma unroll
  for (int mi = 0; mi < 2; ++mi)
#pragma unroll
    for (int r = 0; r < 4; ++r) {
      float m = acc[mi][0][r];
#pragma unroll
      for (int nig = 1; nig < 8; ++nig) m = fmaxf(m, acc[mi][nig][r]);
#pragma unroll
      for (int d = 1; d < 16; d <<= 1) m = fmaxf(m, __shfl_xor(m, d));
      mx[mi][r] = m;
      red[(mi * 16 + lk * 4 + r) * 4 + wave] = m;
    }
  __syncthreads();
#pragma unroll
  for (int mi = 0; mi < 2; ++mi)
#pragma unroll
    for (int r = 0; r < 4; ++r) {
      const int q = mi * 16 + lk * 4 + r;
      mx[mi][r] = fmaxf(fmaxf(red[q * 4], red[q * 4 + 1]),
                        fmaxf(red[q * 4 + 2], red[q * 4 + 3]));
    }
  __syncthreads();

  float sm[2][4];
#pragma unroll
  for (int mi = 0; mi < 2; ++mi)
#pragma unroll
    for (int r = 0; r < 4; ++r) {
      float s = 0.f;
#pragma unroll
      for (int nig = 0; nig < 8; ++nig) {
        const float e = __expf(acc[mi][nig][r] - mx[mi][r]);
        acc[mi][nig][r] = e;
        s += e;
      }
#pragma unroll
      for (int d = 1; d < 16; d <<= 1) s += __shfl_xor(s, d);
      sm[mi][r] = s;
      red[(mi * 16 + lk * 4 + r) * 4 + wave] = s;
    }
  __syncthreads();
#pragma unroll
  for (int mi = 0; mi < 2; ++mi)
#pragma unroll
    for (int r = 0; r < 4; ++r) {
      const int q = mi * 16 + lk * 4 + r;
      sm[mi][r] = 1.f / (red[q * 4] + red[q * 4 + 1] + red[q * 4 + 2] + red[q * 4 + 3]);
    }

  // ---- P -> LDS (Ks aliased as Ps[32][512], chunk-XOR swizzled) ----
#pragma unroll
  for (int mi = 0; mi < 2; ++mi)
#pragma unroll
    for (int nig = 0; nig < 8; ++nig) {
      const int col = (nig >> 2) * 256 + wave * 64 + (nig & 3) * 16 + l16;
#pragma unroll
      for (int r = 0; r < 4; ++r) {
        const int q = mi * 16 + lk * 4 + r;
        const int swz = (((col >> 3) ^ (q & 7)) << 3) | (col & 7);
        Ks[q * 512 + swz] = f2bf(acc[mi][nig][r] * sm[mi][r]);
      }
    }
  __syncthreads();

  // ---- PV: ctx[32 q][64 d] = P @ V^T, V^T streamed from global ----
  const short* vb = Vt + (long long)bh * 32768 + (wave * 16 + l16) * 512 + lk * 8;
  f32x4 pacc[2] = {};
  s16x8 vn = *(const s16x8*)vb;
#pragma unroll
  for (int s = 0; s < 16; ++s) {
    const s16x8 bfr = vn;
    if (s + 1 < 16) vn = *(const s16x8*)(vb + (s + 1) * 32);
    const int ch = ((s * 4 + lk) ^ (l16 & 7)) * 8;
    const s16x8 af0 = *(const s16x8*)&Ks[l16 * 512 + ch];
    const s16x8 af1 = *(const s16x8*)&Ks[(16 + l16) * 512 + ch];
    pacc[0] = mfma16(bfr, af0, pacc[0]);
    pacc[1] = mfma16(bfr, af1, pacc[1]);
  }
#pragma unroll
  for (int mi = 0; mi < 2; ++mi) {
    s16x4 o;
#pragma unroll
    for (int r = 0; r < 4; ++r) o[r] = f2bf(pacc[mi][r]);
    *(s16x4*)&ctx[(long long)(b * 512 + q0 + mi * 16 + l16) * 768 +
                  hh * 64 + wave * 16 + lk * 4] = o;
  }
}

// ---------- fused split-K reduce (bf16 partials) + bias + residual + LN ----------
template<int NS, int MODE>
__global__ __launch_bounds__(256) void ln_red(
    const short* __restrict__ part, const float* __restrict__ bias,
    const float* __restrict__ res, const float* __restrict__ ln,
    float* __restrict__ outf, short* __restrict__ outb,
    const int* __restrict__ hmask) {
  constexpr long long SP = 4096LL * 768;
  const int row = blockIdx.x * 4 + (threadIdx.x >> 6);
  const int lane = threadIdx.x & 63;
  const long long rb = (long long)row * 768;
  float v[12];
  float s = 0.f;
#pragma unroll
  for (int i = 0; i < 3; ++i) {
    const int c4 = lane + (i << 6);
    float4 t = ((const float4*)(res + rb))[c4];
    const float4 bv = ((const float4*)bias)[c4];
    t.x += bv.x; t.y += bv.y; t.z += bv.z; t.w += bv.w;
#pragma unroll
    for (int ss = 0; ss < NS; ++ss) {
      const s16x4 p = *(const s16x4*)&part[ss * SP + rb + c4 * 4];
      t.x += bf2f(p[0]); t.y += bf2f(p[1]); t.z += bf2f(p[2]); t.w += bf2f(p[3]);
    }
    v[i * 4 + 0] = t.x; v[i * 4 + 1] = t.y; v[i * 4 + 2] = t.z; v[i * 4 + 3] = t.w;
    s += t.x + t.y + t.z + t.w;
  }
#pragma unroll
  for (int d = 1; d < 64; d <<= 1) s += __shfl_xor(s, d);
  const float mean = s * (1.f / 768.f);
  float vs = 0.f;
#pragma unroll
  for (int i = 0; i < 12; ++i) { const float dv = v[i] - mean; vs += dv * dv; }
#pragma unroll
  for (int d = 1; d < 64; d <<= 1) vs += __shfl_xor(vs, d);
  const float rstd = rsqrtf(vs * (1.f / 768.f) + 1e-12f);
  int keep = 1;
  if constexpr (MODE == 2) keep = (hmask[row] != 0);
#pragma unroll
  for (int i = 0; i < 3; ++i) {
    const int c4 = lane + (i << 6);
    const float4 g = ((const float4*)ln)[c4];
    const float4 be = ((const float4*)(ln + 768))[c4];
    const float gg[4] = {g.x, g.y, g.z, g.w}, bb[4] = {be.x, be.y, be.z, be.w};
    float resv[4];
#pragma unroll
    for (int j = 0; j < 4; ++j) {
      float yv = (v[i * 4 + j] - mean) * rstd * gg[j] + bb[j];
      if constexpr (MODE == 2) {
        const float a = outf[rb + c4 * 4 + j];
        yv = a + (keep ? yv : 0.f);
      }
      resv[j] = yv;
    }
    float4 of; of.x = resv[0]; of.y = resv[1]; of.z = resv[2]; of.w = resv[3];
    ((float4*)(outf + rb))[c4] = of;
    if constexpr (MODE >= 1) {
      s16x4 ob;
#pragma unroll
      for (int j = 0; j < 4; ++j) ob[j] = f2bf(resv[j]);
      *(s16x4*)&outb[rb + c4 * 4] = ob;
    }
  }
}

// ---------- host ----------
extern "C" void kernel_launch(void* const* d_in, const int* in_sizes, int n_in,
                              void* d_out, int out_size, void* d_ws, size_t ws_size,
                              hipStream_t stream) {
  (void)in_sizes; (void)n_in; (void)out_size; (void)ws_size;
  const float* h      = (const float*)d_in[0];
  const float* amask  = (const float*)d_in[1];
  const int*   hmask  = (const int*)d_in[2];
  const float* mWattn = (const float*)d_in[3];
  const float* mbattn = (const float*)d_in[4];
  const float* mlnA   = (const float*)d_in[5];
  const float* mWi    = (const float*)d_in[6];
  const float* mbi    = (const float*)d_in[7];
  const float* mWo    = (const float*)d_in[8];
  const float* mbo    = (const float*)d_in[9];
  const float* mlnO   = (const float*)d_in[10];
  const float* hWattn = (const float*)d_in[11];
  const float* hbattn = (const float*)d_in[12];
  const float* hlnA   = (const float*)d_in[13];
  const float* hWi    = (const float*)d_in[14];
  const float* hbi    = (const float*)d_in[15];
  const float* hWo    = (const float*)d_in[16];
  const float* hbo    = (const float*)d_in[17];
  const float* hlnO   = (const float*)d_in[18];
  float* out = (float*)d_out;

  char* ws = (char*)d_ws;
  size_t off = 0;
  auto alloc = [&](size_t bytes) {
    void* p = ws + off;
    off += (bytes + 255) & ~(size_t)255;
    return p;
  };
  const long long SC  = 4096LL * 768;
  const long long SC3 = 4096LL * 2304;
  short* wq2  = (short*)alloc(2ull * 2304 * 768 * 2);  // [path][2304][768]
  short* wo2  = (short*)alloc(2ull * 768 * 768 * 2);   // [path][768][768]
  short* wi_m = (short*)alloc(3072ull * 768 * 2);
  short* wi_h = (short*)alloc(3072ull * 768 * 2);
  short* wf_m = (short*)alloc(768ull * 3072 * 2);
  short* wf_h = (short*)alloc(768ull * 3072 * 2);
  short* hbf  = (short*)alloc(4096ull * 768 * 2);
  short* qkv2 = (short*)alloc(2ull * SC3 * 2);           // [path] (V cols unused)
  short* vt2  = (short*)alloc(2ull * 96 * 64 * 512 * 2); // [path]
  short* Pb   = (short*)alloc(96ull * 512 * 512 * 2);    // partials
  short* ctxb = (short*)alloc(2ull * 4096 * 768 * 2);    // [path]
  float* pre1 = (float*)alloc(4096ull * 768 * 4);
  float* attn = (float*)alloc(4096ull * 768 * 4);
  short* abf  = (short*)alloc(4096ull * 768 * 2);
  short* cbf  = (short*)alloc(4096ull * 768 * 2);
  short* mid  = qkv2;        // free in FFN phase
  short* part = Pb;          // [<=4][SC] bf16

  cast_bf16<<<dim3(3072), dim3(256), 0, stream>>>(h, hbf);

  TJobs tj; int tile = 0; int nj = 0;
  auto add = [&](const float* s, short* d, int K, int N) {
    tj.j[nj].src = s; tj.j[nj].dst = d; tj.j[nj].K = K; tj.j[nj].N = N; tj.j[nj].tile0 = tile;
    tile += (K / 32) * (N / 32); nj++;
  };
  const long long WQ = 2304LL * 768;
  add(mWattn,              wq2,                768, 768);
  add(mWattn + 589824,     wq2 + 589824,       768, 768);
  add(mWattn + 2 * 589824, wq2 + 2 * 589824,   768, 768);
  add(mWattn + 3 * 589824, wo2,                768, 768);
  add(mWi,                 wi_m,               768, 3072);
  add(mWo,                 wf_m,               3072, 768);
  add(hWattn,              wq2 + WQ,           768, 768);
  add(hWattn + 589824,     wq2 + WQ + 589824,  768, 768);
  add(hWattn + 2 * 589824, wq2 + WQ + 2 * 589824, 768, 768);
  add(hWattn + 3 * 589824, wo2 + 589824,       768, 768);
  add(hWi,                 wi_h,               768, 3072);
  add(hWo,                 wf_h,               3072, 768);
  transpose_w<<<dim3(tile), dim3(256), 0, stream>>>(tj);

  // ---- QKV projection, BOTH paths in one dispatch (z = path), fused V^T ----
  gemm_bt<128, 128, 64, 64, 3><<<dim3(32, 18, 2), dim3(256), 0, stream>>>(
      hbf, 768, 0, wq2, 768, WQ, qkv2, 2304, SC3, 1, 0,
      mbattn, hbattn, 768, 1, vt2);

  // ---- fused scores+softmax+PV, one dispatch per path (L2 locality) ----
  attn_fused<0><<<dim3(16, 96), dim3(256), 0, stream>>>(
      qkv2, amask, hmask, vt2, ctxb);
  attn_fused<1><<<dim3(16, 96), dim3(256), 0, stream>>>(
      qkv2 + SC3, amask, hmask, vt2 + 3145728, ctxb + SC);

  // ---- out-proj, both paths batched, split-K=2, bf16 partials ----
  gemm_bt<128, 128, 64, 64, 2><<<dim3(32, 6, 4), dim3(256), 0, stream>>>(
      ctxb, 768, SC, wo2, 768, 589824LL, part, 768, SC, 1, 0,
      nullptr, nullptr, 384, 2, nullptr);
  ln_red<2, 0><<<dim3(1024), dim3(256), 0, stream>>>(
      part, mbattn + 2304, h, mlnA, attn, nullptr, nullptr);
  ln_red<2, 1><<<dim3(1024), dim3(256), 0, stream>>>(
      part + 2 * SC, hbattn + 2304, h, hlnA, pre1, abf, nullptr);

  // ---- hier FFN ----
  gemm_bt<128, 128, 64, 64, 1><<<dim3(32, 24, 1), dim3(256), 0, stream>>>(
      abf, 768, 0, wi_h, 768, 0, mid, 3072, 0, 1, 0, hbi, nullptr, 768, 1, nullptr);
  gemm_bt<128, 128, 64, 64, 2><<<dim3(32, 6, 4), dim3(256), 0, stream>>>(
      mid, 3072, 0, wf_h, 3072, 0, part, 768, SC, 1, 0, nullptr, nullptr, 768, 4, nullptr);
  ln_red<4, 2><<<dim3(1024), dim3(256), 0, stream>>>(
      part, hbo, pre1, hlnO, attn, cbf, hmask);

  // ---- final FFN ----
  gemm_bt<128, 128, 64, 64, 1><<<dim3(32, 24, 1), dim3(256), 0, stream>>>(
      cbf, 768, 0, wi_m, 768, 0, mid, 3072, 0, 1, 0, mbi, nullptr, 768, 1, nullptr);
  gemm_bt<128, 128, 64, 64, 2><<<dim3(32, 6, 4), dim3(256), 0, stream>>>(
      mid, 3072, 0, wf_m, 3072, 0, part, 768, SC, 1, 0, nullptr, nullptr, 768, 4, nullptr);
  ln_red<4, 0><<<dim3(1024), dim3(256), 0, stream>>>(
      part, mbo, attn, mlnO, out, nullptr, nullptr);
}

// Round 16
// 327.817 us; speedup vs baseline: 1.0803x; 1.0803x over previous
//
#include <hip/hip_runtime.h>
#include <hip/hip_bf16.h>

#define DI __device__ __forceinline__

typedef __attribute__((ext_vector_type(4))) float  f32x4;
typedef __attribute__((ext_vector_type(8))) short  s16x8;
typedef __attribute__((ext_vector_type(4))) short  s16x4;
typedef __attribute__((ext_vector_type(8))) __bf16 bf16x8;

// ---------- helpers ----------
DI short f2bf(float f) {
  union { float f; unsigned u; } v; v.f = f;
  unsigned r = v.u + 0x7fffu + ((v.u >> 16) & 1u);   // RNE
  return (short)(r >> 16);
}
DI float bf2f(short s) {
  union { unsigned u; float f; } v; v.u = ((unsigned)(unsigned short)s) << 16;
  return v.f;
}

DI f32x4 mfma16(s16x8 a, s16x8 b, f32x4 c) {
  return __builtin_amdgcn_mfma_f32_16x16x32_bf16(
      __builtin_bit_cast(bf16x8, a), __builtin_bit_cast(bf16x8, b), c, 0, 0, 0);
}

typedef const __attribute__((address_space(1))) unsigned* gas_p;
typedef __attribute__((address_space(3))) unsigned* las_p;
DI void gload16(const void* g, void* l) {
  __builtin_amdgcn_global_load_lds((gas_p)g, (las_p)l, 16, 0, 0);
}

template<int N> DI void wait_vmcnt() {
  asm volatile("s_waitcnt vmcnt(%0)" :: "n"(N) : "memory");
}

// ---------- f32 -> bf16 cast ----------
__global__ __launch_bounds__(256) void cast_bf16(const float* __restrict__ x,
                                                 short* __restrict__ y) {
  const int i = (blockIdx.x * 256 + threadIdx.x) * 4;
  const float4 t = *(const float4*)&x[i];
  s16x4 o;
  o[0] = f2bf(t.x); o[1] = f2bf(t.y); o[2] = f2bf(t.z); o[3] = f2bf(t.w);
  *(s16x4*)&y[i] = o;
}

// ---------- weight transpose+cast: W[K,N] f32 -> Wt[N,K] bf16 ----------
struct TJob { const float* src; short* dst; int K, N, tile0; };
struct TJobs { TJob j[12]; };

__global__ __launch_bounds__(256) void transpose_w(TJobs jobs) {
  __shared__ float T[32][33];
  const int t = blockIdx.x;
  int ji = 0;
#pragma unroll
  for (int i = 1; i < 12; ++i) if (jobs.j[i].tile0 <= t) ji = i;
  const float* src = jobs.j[ji].src;
  short* dst = jobs.j[ji].dst;
  const int K = jobs.j[ji].K, N = jobs.j[ji].N;
  const int lt = t - jobs.j[ji].tile0;
  const int tn = N >> 5;
  const int n0 = (lt % tn) << 5, k0 = (lt / tn) << 5;
  const int tid = threadIdx.x;
#pragma unroll
  for (int i = 0; i < 4; ++i) {
    const int c = i * 256 + tid, r = c >> 5, cc = c & 31;
    T[cc][r] = src[(long long)(k0 + r) * N + n0 + cc];
  }
  __syncthreads();
#pragma unroll
  for (int i = 0; i < 4; ++i) {
    const int c = i * 256 + tid, r = c >> 5, cc = c & 31;
    dst[(long long)(n0 + r) * K + k0 + cc] = f2bf(T[r][cc]);
  }
}

// ---------- 4-wave MFMA GEMM: C = A[M,K] @ B[N,K]^T ----------
// 3-ring LDS, counted vmcnt, raw s_barrier, XOR-swizzled LDS (0 conflicts),
// swapped-operand MFMA (lane holds 4 consecutive C-cols).
// (T1 XCD swizzle REMOVED: with z-batched grids it broke L2 chunking —
//  r14 measured FETCH 33.9 -> 54.4 MB on QKV.)
// z = zb*nSplit+zs; zs selects K-slice.  bias2: per-zb bias (batched paths).
// EPI 0: bf16 +bias. EPI 1: bf16 gelu(x+bias). EPI 2: bf16 raw partial.
// EPI 3: bf16 +bias for cols<1536; cols>=1536 write ONLY V^T to
//        vtOut[zb][bh][d][s] (qkv V-columns are dead downstream).
template<int BM, int BN, int WM, int WN, int EPI>
__global__ __launch_bounds__(256) void gemm_bt(
    const short* __restrict__ A, int lda, long long sA,
    const short* __restrict__ B, int ldb, long long sB,
    void* __restrict__ Cv, int ldc,
    long long cOuter, int cInner, int cStride,
    const float* __restrict__ bias, const float* __restrict__ bias2,
    int K, int nSplit,
    short* __restrict__ vtOut) {
  constexpr int BK = 32;
  constexpr int WNW = BN / WN;
  constexpr int MFR = WM / 16, NFR = WN / 16;
  constexpr int ALD = BM / 64;
  constexpr int BLD = BN / 64;
  constexpr int LPT = ALD + BLD;

  __shared__ short As[3][BM * BK];
  __shared__ short Bs[3][BN * BK];

  const int z = blockIdx.z;
  const int zb = z / nSplit, zs = z - zb * nSplit;
  const short* Ab = A + (long long)zb * sA + (long long)zs * K;
  const short* Bb = B + (long long)zb * sB + (long long)zs * K;
  const long long cOff = (long long)(z / cInner) * cOuter + (long long)(z % cInner) * cStride;
  const float* bi = (bias2 && zb) ? bias2 : bias;

  const int bm = blockIdx.x * BM;
  const int bn = blockIdx.y * BN;
  const int tid = threadIdx.x;
  const int wave = tid >> 6, lane = tid & 63;
  const int wm = (wave / WNW) * WM;
  const int wn = (wave % WNW) * WN;
  const int l16 = lane & 15, lk = lane >> 4;

  const int scol = ((tid & 3) ^ ((tid >> 3) & 3)) * 8;
  const short* aBase = Ab + (long long)(bm + (tid >> 2)) * lda + scol;
  const short* bBase = Bb + (long long)(bn + (tid >> 2)) * ldb + scol;
  const int ldsOff = wave * 64 * 8;
  const int rslot = (lk ^ ((l16 >> 1) & 3)) * 8;

  f32x4 acc[MFR][NFR] = {};

  auto stage = [&](int buf, int kt) {
#pragma unroll
    for (int i = 0; i < ALD; ++i)
      gload16(aBase + kt + (long long)(i * 64) * lda, &As[buf][i * 2048 + ldsOff]);
#pragma unroll
    for (int i = 0; i < BLD; ++i)
      gload16(bBase + kt + (long long)(i * 64) * ldb, &Bs[buf][i * 2048 + ldsOff]);
  };

  const int nt = K / BK;
  stage(0, 0);
  if (nt > 1) stage(1, BK);
  int cur = 0;
  for (int t = 0; t < nt; ++t) {
    if (t + 1 < nt) wait_vmcnt<LPT>();
    else            wait_vmcnt<0>();
    __builtin_amdgcn_s_barrier();
    s16x8 af[MFR], bfr[NFR];
#pragma unroll
    for (int mi = 0; mi < MFR; ++mi)
      af[mi] = *(const s16x8*)&As[cur][(wm + mi * 16 + l16) * BK + rslot];
#pragma unroll
    for (int ni = 0; ni < NFR; ++ni)
      bfr[ni] = *(const s16x8*)&Bs[cur][(wn + ni * 16 + l16) * BK + rslot];
#pragma unroll
    for (int mi = 0; mi < MFR; ++mi)
#pragma unroll
      for (int ni = 0; ni < NFR; ++ni)
        acc[mi][ni] = mfma16(bfr[ni], af[mi], acc[mi][ni]);
    if (t + 2 < nt) {
      const int nb = cur + 2 >= 3 ? cur - 1 : cur + 2;
      stage(nb, (t + 2) * BK);
    }
    cur = (cur + 1 == 3) ? 0 : cur + 1;
  }

#pragma unroll
  for (int mi = 0; mi < MFR; ++mi) {
    const int row = bm + wm + mi * 16 + l16;
#pragma unroll
    for (int ni = 0; ni < NFR; ++ni) {
      const int col = bn + wn + ni * 16 + lk * 4;
      const long long idx = cOff + (long long)row * ldc + col;
      f32x4 bv = {};
      if (EPI != 2 && bi) bv = *(const f32x4*)&bi[col];
      f32x4 v = acc[mi][ni] + bv;
      if constexpr (EPI == 0 || EPI == 2 || EPI == 3) {
        s16x4 o;
#pragma unroll
        for (int r = 0; r < 4; ++r) o[r] = f2bf(v[r]);
        if constexpr (EPI == 3) {
          if (col >= 1536) {   // block-uniform (128-tile never straddles 1536)
            const int b = row >> 9, s = row & 511;
            const int hc = col - 1536;
            const int bh = b * 12 + (hc >> 6);
            const int d0 = hc & 63;
            short* vp = vtOut + (long long)zb * 3145728 +
                        (long long)bh * 32768 + (long long)d0 * 512 + s;
#pragma unroll
            for (int r = 0; r < 4; ++r) vp[r * 512] = o[r];
          } else {
            *(s16x4*)&((short*)Cv)[idx] = o;
          }
        } else {
          *(s16x4*)&((short*)Cv)[idx] = o;
        }
      } else {  // EPI 1
        s16x4 o;
#pragma unroll
        for (int r = 0; r < 4; ++r) {
          const float g = 0.5f * v[r] * (1.f + erff(v[r] * 0.70710678118654752f));
          o[r] = f2bf(g);
        }
        *(s16x4*)&((short*)Cv)[idx] = o;
      }
    }
  }
}

// ---------- fused scores + softmax + PV -> ctx (bf16), one path per dispatch ----------
template<int HIER>
__global__ __launch_bounds__(256) void attn_fused(
    const short* __restrict__ QKV,
    const float* __restrict__ amask,
    const int* __restrict__ hmask,
    const short* __restrict__ Vt,
    short* __restrict__ ctx) {
  __shared__ short Qs[32 * 64];
  __shared__ short Ks[256 * 64];        // reused as Ps[32][512] after scores
  __shared__ float red[32 * 4];
  __shared__ int   hm[512];

  const int bh = blockIdx.y;
  const int b = bh / 12, hh = bh % 12;
  const int q0 = blockIdx.x * 32;
  const int tid = threadIdx.x;
  const int wave = tid >> 6, lane = tid & 63;
  const int l16 = lane & 15, lk = lane >> 4;
  const long long rowbase = (long long)(b * 512) * 2304 + hh * 64;

  {
    const int c = tid;
    const int d8 = ((c & 7) ^ ((c >> 3) & 7)) * 8;
    gload16(QKV + rowbase + (long long)(q0 + (c >> 3)) * 2304 + d8,
            &Qs[wave * 64 * 8]);
  }
  if constexpr (HIER) {
    for (int i = tid; i < 512; i += 256) hm[i] = hmask[b * 512 + i];
  }

  f32x4 acc[2][8] = {};
#pragma unroll
  for (int kc = 0; kc < 2; ++kc) {
    if (kc) __syncthreads();
#pragma unroll
    for (int i = 0; i < 8; ++i) {
      const int c = i * 256 + tid;
      const int d8 = ((c & 7) ^ ((c >> 3) & 7)) * 8;
      gload16(QKV + rowbase + 768 + (long long)(kc * 256 + (c >> 3)) * 2304 + d8,
              &Ks[(i * 256 + wave * 64) * 8]);
    }
    __syncthreads();
#pragma unroll
    for (int ks = 0; ks < 2; ++ks) {
      s16x8 af[2], bfr[4];
#pragma unroll
      for (int mi = 0; mi < 2; ++mi)
        af[mi] = *(const s16x8*)&Qs[(mi * 16 + l16) * 64 +
                                    (((ks * 4 + lk) ^ (l16 & 7)) * 8)];
#pragma unroll
      for (int ni = 0; ni < 4; ++ni)
        bfr[ni] = *(const s16x8*)&Ks[(wave * 64 + ni * 16 + l16) * 64 +
                                     (((ks * 4 + lk) ^ (l16 & 7)) * 8)];
#pragma unroll
      for (int mi = 0; mi < 2; ++mi)
#pragma unroll
        for (int ni = 0; ni < 4; ++ni)
          acc[mi][kc * 4 + ni] = mfma16(af[mi], bfr[ni], acc[mi][kc * 4 + ni]);
    }
  }

  int gq[2][4];
  if constexpr (HIER) {
#pragma unroll
    for (int mi = 0; mi < 2; ++mi)
#pragma unroll
      for (int r = 0; r < 4; ++r)
        gq[mi][r] = hm[q0 + mi * 16 + lk * 4 + r];
  }
  int hk[8]; float am[8];
#pragma unroll
  for (int nig = 0; nig < 8; ++nig) {
    const int col = (nig >> 2) * 256 + wave * 64 + (nig & 3) * 16 + l16;
    if constexpr (HIER) hk[nig] = hm[col];
    else                am[nig] = amask[b * 512 + col];
  }
#pragma unroll
  for (int mi = 0; mi < 2; ++mi)
#pragma unroll
    for (int nig = 0; nig < 8; ++nig)
#pragma unroll
      for (int r = 0; r < 4; ++r) {
        float v = acc[mi][nig][r] * 0.125f;
        if constexpr (HIER) v += (hk[nig] == gq[mi][r]) ? 0.f : -10000.f;
        else                v += am[nig];
        acc[mi][nig][r] = v;
      }

  float mx[2][4];
#pragma unroll
  for (int mi = 0; mi < 2; ++mi)
#pragma unroll
    for (int r = 0; r < 4; ++r) {
      float m = acc[mi][0][r];
#pragma unroll
      for (int nig = 1; nig < 8; ++nig) m = fmaxf(m, acc[mi][nig][r]);
#pragma unroll
      for (int d = 1; d < 16; d <<= 1) m = fmaxf(m, __shfl_xor(m, d));
      mx[mi][r] = m;
      red[(mi * 16 + lk * 4 + r) * 4 + wave] = m;
    }
  __syncthreads();
#pragma unroll
  for (int mi = 0; mi < 2; ++mi)
#pragma unroll
    for (int r = 0; r < 4; ++r) {
      const int q = mi * 16 + lk * 4 + r;
      mx[mi][r] = fmaxf(fmaxf(red[q * 4], red[q * 4 + 1]),
                        fmaxf(red[q * 4 + 2], red[q * 4 + 3]));
    }
  __syncthreads();

  float sm[2][4];
#pragma unroll
  for (int mi = 0; mi < 2; ++mi)
#pragma unroll
    for (int r = 0; r < 4; ++r) {
      float s = 0.f;
#pragma unroll
      for (int nig = 0; nig < 8; ++nig) {
        const float e = __expf(acc[mi][nig][r] - mx[mi][r]);
        acc[mi][nig][r] = e;
        s += e;
      }
#pragma unroll
      for (int d = 1; d < 16; d <<= 1) s += __shfl_xor(s, d);
      sm[mi][r] = s;
      red[(mi * 16 + lk * 4 + r) * 4 + wave] = s;
    }
  __syncthreads();
#pragma unroll
  for (int mi = 0; mi < 2; ++mi)
#pragma unroll
    for (int r = 0; r < 4; ++r) {
      const int q = mi * 16 + lk * 4 + r;
      sm[mi][r] = 1.f / (red[q * 4] + red[q * 4 + 1] + red[q * 4 + 2] + red[q * 4 + 3]);
    }

  // ---- P -> LDS (Ks aliased as Ps[32][512], chunk-XOR swizzled) ----
#pragma unroll
  for (int mi = 0; mi < 2; ++mi)
#pragma unroll
    for (int nig = 0; nig < 8; ++nig) {
      const int col = (nig >> 2) * 256 + wave * 64 + (nig & 3) * 16 + l16;
#pragma unroll
      for (int r = 0; r < 4; ++r) {
        const int q = mi * 16 + lk * 4 + r;
        const int swz = (((col >> 3) ^ (q & 7)) << 3) | (col & 7);
        Ks[q * 512 + swz] = f2bf(acc[mi][nig][r] * sm[mi][r]);
      }
    }
  __syncthreads();

  // ---- PV: ctx[32 q][64 d] = P @ V^T, V^T streamed from global ----
  const short* vb = Vt + (long long)bh * 32768 + (wave * 16 + l16) * 512 + lk * 8;
  f32x4 pacc[2] = {};
  s16x8 vn = *(const s16x8*)vb;
#pragma unroll
  for (int s = 0; s < 16; ++s) {
    const s16x8 bfr = vn;
    if (s + 1 < 16) vn = *(const s16x8*)(vb + (s + 1) * 32);
    const int ch = ((s * 4 + lk) ^ (l16 & 7)) * 8;
    const s16x8 af0 = *(const s16x8*)&Ks[l16 * 512 + ch];
    const s16x8 af1 = *(const s16x8*)&Ks[(16 + l16) * 512 + ch];
    pacc[0] = mfma16(bfr, af0, pacc[0]);
    pacc[1] = mfma16(bfr, af1, pacc[1]);
  }
#pragma unroll
  for (int mi = 0; mi < 2; ++mi) {
    s16x4 o;
#pragma unroll
    for (int r = 0; r < 4; ++r) o[r] = f2bf(pacc[mi][r]);
    *(s16x4*)&ctx[(long long)(b * 512 + q0 + mi * 16 + l16) * 768 +
                  hh * 64 + wave * 16 + lk * 4] = o;
  }
}

// ---------- fused split-K reduce (bf16 partials) + bias + residual + LN ----------
template<int NS, int MODE>
__global__ __launch_bounds__(256) void ln_red(
    const short* __restrict__ part, const float* __restrict__ bias,
    const float* __restrict__ res, const float* __restrict__ ln,
    float* __restrict__ outf, short* __restrict__ outb,
    const int* __restrict__ hmask) {
  constexpr long long SP = 4096LL * 768;
  const int row = blockIdx.x * 4 + (threadIdx.x >> 6);
  const int lane = threadIdx.x & 63;
  const long long rb = (long long)row * 768;
  float v[12];
  float s = 0.f;
#pragma unroll
  for (int i = 0; i < 3; ++i) {
    const int c4 = lane + (i << 6);
    float4 t = ((const float4*)(res + rb))[c4];
    const float4 bv = ((const float4*)bias)[c4];
    t.x += bv.x; t.y += bv.y; t.z += bv.z; t.w += bv.w;
#pragma unroll
    for (int ss = 0; ss < NS; ++ss) {
      const s16x4 p = *(const s16x4*)&part[ss * SP + rb + c4 * 4];
      t.x += bf2f(p[0]); t.y += bf2f(p[1]); t.z += bf2f(p[2]); t.w += bf2f(p[3]);
    }
    v[i * 4 + 0] = t.x; v[i * 4 + 1] = t.y; v[i * 4 + 2] = t.z; v[i * 4 + 3] = t.w;
    s += t.x + t.y + t.z + t.w;
  }
#pragma unroll
  for (int d = 1; d < 64; d <<= 1) s += __shfl_xor(s, d);
  const float mean = s * (1.f / 768.f);
  float vs = 0.f;
#pragma unroll
  for (int i = 0; i < 12; ++i) { const float dv = v[i] - mean; vs += dv * dv; }
#pragma unroll
  for (int d = 1; d < 64; d <<= 1) vs += __shfl_xor(vs, d);
  const float rstd = rsqrtf(vs * (1.f / 768.f) + 1e-12f);
  int keep = 1;
  if constexpr (MODE == 2) keep = (hmask[row] != 0);
#pragma unroll
  for (int i = 0; i < 3; ++i) {
    const int c4 = lane + (i << 6);
    const float4 g = ((const float4*)ln)[c4];
    const float4 be = ((const float4*)(ln + 768))[c4];
    const float gg[4] = {g.x, g.y, g.z, g.w}, bb[4] = {be.x, be.y, be.z, be.w};
    float resv[4];
#pragma unroll
    for (int j = 0; j < 4; ++j) {
      float yv = (v[i * 4 + j] - mean) * rstd * gg[j] + bb[j];
      if constexpr (MODE == 2) {
        const float a = outf[rb + c4 * 4 + j];
        yv = a + (keep ? yv : 0.f);
      }
      resv[j] = yv;
    }
    float4 of; of.x = resv[0]; of.y = resv[1]; of.z = resv[2]; of.w = resv[3];
    ((float4*)(outf + rb))[c4] = of;
    if constexpr (MODE >= 1) {
      s16x4 ob;
#pragma unroll
      for (int j = 0; j < 4; ++j) ob[j] = f2bf(resv[j]);
      *(s16x4*)&outb[rb + c4 * 4] = ob;
    }
  }
}

// ---------- host ----------
extern "C" void kernel_launch(void* const* d_in, const int* in_sizes, int n_in,
                              void* d_out, int out_size, void* d_ws, size_t ws_size,
                              hipStream_t stream) {
  (void)in_sizes; (void)n_in; (void)out_size; (void)ws_size;
  const float* h      = (const float*)d_in[0];
  const float* amask  = (const float*)d_in[1];
  const int*   hmask  = (const int*)d_in[2];
  const float* mWattn = (const float*)d_in[3];
  const float* mbattn = (const float*)d_in[4];
  const float* mlnA   = (const float*)d_in[5];
  const float* mWi    = (const float*)d_in[6];
  const float* mbi    = (const float*)d_in[7];
  const float* mWo    = (const float*)d_in[8];
  const float* mbo    = (const float*)d_in[9];
  const float* mlnO   = (const float*)d_in[10];
  const float* hWattn = (const float*)d_in[11];
  const float* hbattn = (const float*)d_in[12];
  const float* hlnA   = (const float*)d_in[13];
  const float* hWi    = (const float*)d_in[14];
  const float* hbi    = (const float*)d_in[15];
  const float* hWo    = (const float*)d_in[16];
  const float* hbo    = (const float*)d_in[17];
  const float* hlnO   = (const float*)d_in[18];
  float* out = (float*)d_out;

  char* ws = (char*)d_ws;
  size_t off = 0;
  auto alloc = [&](size_t bytes) {
    void* p = ws + off;
    off += (bytes + 255) & ~(size_t)255;
    return p;
  };
  const long long SC  = 4096LL * 768;
  const long long SC3 = 4096LL * 2304;
  short* wq2  = (short*)alloc(2ull * 2304 * 768 * 2);  // [path][2304][768]
  short* wo2  = (short*)alloc(2ull * 768 * 768 * 2);   // [path][768][768]
  short* wi_m = (short*)alloc(3072ull * 768 * 2);
  short* wi_h = (short*)alloc(3072ull * 768 * 2);
  short* wf_m = (short*)alloc(768ull * 3072 * 2);
  short* wf_h = (short*)alloc(768ull * 3072 * 2);
  short* hbf  = (short*)alloc(4096ull * 768 * 2);
  short* qkv2 = (short*)alloc(2ull * SC3 * 2);           // [path] (V cols unused)
  short* vt2  = (short*)alloc(2ull * 96 * 64 * 512 * 2); // [path]
  short* Pb   = (short*)alloc(96ull * 512 * 512 * 2);    // partials
  short* ctxb = (short*)alloc(2ull * 4096 * 768 * 2);    // [path]
  float* pre1 = (float*)alloc(4096ull * 768 * 4);
  float* attn = (float*)alloc(4096ull * 768 * 4);
  short* abf  = (short*)alloc(4096ull * 768 * 2);
  short* cbf  = (short*)alloc(4096ull * 768 * 2);
  short* mid  = qkv2;        // free in FFN phase
  short* part = Pb;          // [<=4][SC] bf16

  cast_bf16<<<dim3(3072), dim3(256), 0, stream>>>(h, hbf);

  TJobs tj; int tile = 0; int nj = 0;
  auto add = [&](const float* s, short* d, int K, int N) {
    tj.j[nj].src = s; tj.j[nj].dst = d; tj.j[nj].K = K; tj.j[nj].N = N; tj.j[nj].tile0 = tile;
    tile += (K / 32) * (N / 32); nj++;
  };
  const long long WQ = 2304LL * 768;
  add(mWattn,              wq2,                768, 768);
  add(mWattn + 589824,     wq2 + 589824,       768, 768);
  add(mWattn + 2 * 589824, wq2 + 2 * 589824,   768, 768);
  add(mWattn + 3 * 589824, wo2,                768, 768);
  add(mWi,                 wi_m,               768, 3072);
  add(mWo,                 wf_m,               3072, 768);
  add(hWattn,              wq2 + WQ,           768, 768);
  add(hWattn + 589824,     wq2 + WQ + 589824,  768, 768);
  add(hWattn + 2 * 589824, wq2 + WQ + 2 * 589824, 768, 768);
  add(hWattn + 3 * 589824, wo2 + 589824,       768, 768);
  add(hWi,                 wi_h,               768, 3072);
  add(hWo,                 wf_h,               3072, 768);
  transpose_w<<<dim3(tile), dim3(256), 0, stream>>>(tj);

  // ---- QKV projection, BOTH paths in one dispatch (z = path), fused V^T ----
  gemm_bt<128, 128, 64, 64, 3><<<dim3(32, 18, 2), dim3(256), 0, stream>>>(
      hbf, 768, 0, wq2, 768, WQ, qkv2, 2304, SC3, 1, 0,
      mbattn, hbattn, 768, 1, vt2);

  // ---- fused scores+softmax+PV, one dispatch per path (L2 locality) ----
  attn_fused<0><<<dim3(16, 96), dim3(256), 0, stream>>>(
      qkv2, amask, hmask, vt2, ctxb);
  attn_fused<1><<<dim3(16, 96), dim3(256), 0, stream>>>(
      qkv2 + SC3, amask, hmask, vt2 + 3145728, ctxb + SC);

  // ---- out-proj, both paths batched, split-K=2, bf16 partials ----
  gemm_bt<128, 128, 64, 64, 2><<<dim3(32, 6, 4), dim3(256), 0, stream>>>(
      ctxb, 768, SC, wo2, 768, 589824LL, part, 768, SC, 1, 0,
      nullptr, nullptr, 384, 2, nullptr);
  ln_red<2, 0><<<dim3(1024), dim3(256), 0, stream>>>(
      part, mbattn + 2304, h, mlnA, attn, nullptr, nullptr);
  ln_red<2, 1><<<dim3(1024), dim3(256), 0, stream>>>(
      part + 2 * SC, hbattn + 2304, h, hlnA, pre1, abf, nullptr);

  // ---- hier FFN ----
  gemm_bt<128, 128, 64, 64, 1><<<dim3(32, 24, 1), dim3(256), 0, stream>>>(
      abf, 768, 0, wi_h, 768, 0, mid, 3072, 0, 1, 0, hbi, nullptr, 768, 1, nullptr);
  gemm_bt<128, 128, 64, 64, 2><<<dim3(32, 6, 4), dim3(256), 0, stream>>>(
      mid, 3072, 0, wf_h, 3072, 0, part, 768, SC, 1, 0, nullptr, nullptr, 768, 4, nullptr);
  ln_red<4, 2><<<dim3(1024), dim3(256), 0, stream>>>(
      part, hbo, pre1, hlnO, attn, cbf, hmask);

  // ---- final FFN ----
  gemm_bt<128, 128, 64, 64, 1><<<dim3(32, 24, 1), dim3(256), 0, stream>>>(
      cbf, 768, 0, wi_m, 768, 0, mid, 3072, 0, 1, 0, mbi, nullptr, 768, 1, nullptr);
  gemm_bt<128, 128, 64, 64, 2><<<dim3(32, 6, 4), dim3(256), 0, stream>>>(
      mid, 3072, 0, wf_m, 3072, 0, part, 768, SC, 1, 0, nullptr, nullptr, 768, 4, nullptr);
  ln_red<4, 0><<<dim3(1024), dim3(256), 0, stream>>>(
      part, mbo, attn, mlnO, out, nullptr, nullptr);
}